// Round 9
// baseline (468.579 us; speedup 1.0000x reference)
//
#include <hip/hip_runtime.h>

typedef __attribute__((ext_vector_type(8))) short bf16x8;
typedef __attribute__((ext_vector_type(4))) float f32x4;
typedef unsigned short ushort_t;
typedef unsigned int uint32;

#define TILE 64
#define N_EDGES 1600000
#define NT (N_EDGES / TILE) /* 25000 */
#define GRID 768            /* 3 blocks/CU x 256 CU */

// LDS (ushorts). W1 stays LIVE in LDS (kk=1,2 A-frags read per iter).
// Per-wave col/h buffers follow; W2 staging (4352 us) overlaps the wave-buffer
// region (pre-loop only, barrier-separated).
// CSTR=104 / HSTR=136: all b128/b64 accesses at minimum bank aliasing.
#define CSTR 104
#define HSTR 136
#define W1_US (128 * CSTR)              /* 13312 us: W1^T, k contiguous, LIVE */
#define WBUF (16 * HSTR)                /* 2176 us per-wave col/h (aliased) buffer */
#define SMEM_USHORTS (W1_US + 4 * WBUF) /* 22016 us = 44032 B -> 3 blocks/CU */

__device__ __forceinline__ ushort_t f2bf(float x) {
    uint32 u = __builtin_bit_cast(uint32, x);
    u += 0x7FFFu + ((u >> 16) & 1u);          // round-to-nearest-even
    return (ushort_t)(u >> 16);
}
__device__ __forceinline__ uint32 cvt_pk_bf16(float lo, float hi) {
    uint32 r;
    asm("v_cvt_pk_bf16_f32 %0, %1, %2" : "=v"(r) : "v"(lo), "v"(hi));
    return r;
}
__device__ __forceinline__ void store_bf16x8(ushort_t* dst, f32x4 a, f32x4 b) {
    uint4 p;
    p.x = cvt_pk_bf16(a[0], a[1]);
    p.y = cvt_pk_bf16(a[2], a[3]);
    p.z = cvt_pk_bf16(b[0], b[1]);
    p.w = cvt_pk_bf16(b[2], b[3]);
    *reinterpret_cast<uint4*>(dst) = p;
}

__global__ __launch_bounds__(256, 3)
void edge_mlp_kernel(const float* __restrict__ edge_feats,
                     const float* __restrict__ node_feats,
                     const int* __restrict__ senders,
                     const int* __restrict__ receivers,
                     const float* __restrict__ W1,
                     const float* __restrict__ b1,
                     const float* __restrict__ W2,
                     const float* __restrict__ b2,
                     float* __restrict__ out)
{
    __shared__ __align__(16) ushort_t smem[SMEM_USHORTS];
    ushort_t* w1t = smem;                   // [128][CSTR] W1^T, k contiguous, LIVE all kernel

    const int tid = threadIdx.x;
    const int l   = tid & 63;
    const int llo = l & 15;
    const int lhi = l >> 4;
    const int w   = tid >> 6;            // wave id 0..3
    const int r   = l >> 2;              // 0..15: edge row this thread stages
    const int q   = l & 3;               // 0..3: 8-float chunk within a 32-feat vector

    // ---- one-time: stage W1 (LDS, live) + W2 (LDS, transient) ----
    {
        ushort_t* w2t = smem + W1_US;    // [32][HSTR], n contiguous (dead after hoist)
        for (int idx = tid; idx < 96 * 128; idx += 256) {
            int k = idx >> 7, n = idx & 127;               // W1[k][n], coalesced read
            w1t[n * CSTR + k] = f2bf(W1[idx]);
        }
        for (int idx = tid; idx < 128 * 32; idx += 256) {
            int n = idx >> 5, o = idx & 31;                // W2[n][o], coalesced read
            w2t[o * HSTR + n] = f2bf(W2[idx]);
        }
    }
    __syncthreads();

    // partial hoist: W1 kk=0 slice (8 frags) + all of W2 (8 frags) -> registers
    bf16x8 w1f0[8];
#pragma unroll
    for (int ni = 0; ni < 8; ++ni)
        w1f0[ni] = *reinterpret_cast<const bf16x8*>(
            smem + (ni * 16 + llo) * CSTR + lhi * 8);
    bf16x8 w2f[2][4];
#pragma unroll
    for (int oi = 0; oi < 2; ++oi)
#pragma unroll
        for (int kk = 0; kk < 4; ++kk)
            w2f[oi][kk] = *reinterpret_cast<const bf16x8*>(
                smem + W1_US + (oi * 16 + llo) * HSTR + kk * 32 + lhi * 8);

    // bias fragments, used as accumulator INIT (C-in of first MFMA)
    f32x4 b1v[8], b2v[2];
#pragma unroll
    for (int ni = 0; ni < 8; ++ni)
        b1v[ni] = *reinterpret_cast<const f32x4*>(b1 + ni * 16 + lhi * 4);
#pragma unroll
    for (int oi = 0; oi < 2; ++oi)
        b2v[oi] = *reinterpret_cast<const f32x4*>(b2 + oi * 16 + lhi * 4);

    __syncthreads();   // W2 staging dead; region becomes per-wave buffers

    ushort_t* buf = smem + W1_US + w * WBUF;  // per-wave col/h (aliased) buffer

    const int stride = gridDim.x;
    const int last = NT - 1;
    int t = blockIdx.x;

    // ---- pipeline prologue: gathers(t) + indices(t+stride), coalesced (r,q) map ----
    int eS = t * TILE + w * 16 + r;
    int si_c = senders[eS], ri_c = receivers[eS];
    f32x4 ea, eb, sa, sb, ra, rb;
    {
        const f32x4* efp = reinterpret_cast<const f32x4*>(edge_feats + (size_t)eS * 32) + q * 2;
        ea = efp[0]; eb = efp[1];
        const f32x4* sp = reinterpret_cast<const f32x4*>(node_feats + (size_t)si_c * 32) + q * 2;
        sa = sp[0]; sb = sp[1];
        const f32x4* rp = reinterpret_cast<const f32x4*>(node_feats + (size_t)ri_c * 32) + q * 2;
        ra = rp[0]; rb = rp[1];
    }
    int ts1 = t + stride; ts1 = ts1 <= last ? ts1 : last;
    int eS1 = ts1 * TILE + w * 16 + r;
    int si_n = senders[eS1], ri_n = receivers[eS1];

    for (; t < NT; t += stride) {
        // ---- 1. stage col(t) from prefetched regs (wave-local, no barrier) ----
        ushort_t* cw = buf + r * CSTR + q * 8;
        store_bf16x8(cw,      ea, eb);
        store_bf16x8(cw + 32, sa, sb);
        store_bf16x8(cw + 64, ra, rb);

        // ---- 2. issue gathers for t+stride (indices prefetched last iteration) ----
        int tn = t + stride; tn = tn <= last ? tn : last;
        {
            int eN = tn * TILE + w * 16 + r;
            const f32x4* efp = reinterpret_cast<const f32x4*>(edge_feats + (size_t)eN * 32) + q * 2;
            ea = efp[0]; eb = efp[1];   // safe: cur values already staged above
            const f32x4* sp = reinterpret_cast<const f32x4*>(node_feats + (size_t)si_n * 32) + q * 2;
            sa = sp[0]; sb = sp[1];
            const f32x4* rp = reinterpret_cast<const f32x4*>(node_feats + (size_t)ri_n * 32) + q * 2;
            ra = rp[0]; rb = rp[1];
        }
        // ---- 3. issue indices for t+2*stride ----
        int tn2 = t + 2 * stride; tn2 = tn2 <= last ? tn2 : last;
        int eN2 = tn2 * TILE + w * 16 + r;
        si_n = senders[eN2]; ri_n = receivers[eN2];

        // ---- 4. GEMM1: kk=0 A-frags from regs, kk=1,2 from LDS ----
        f32x4 acc1[8];
#pragma unroll
        for (int ni = 0; ni < 8; ++ni) acc1[ni] = b1v[ni];   // bias as C-in
        const ushort_t* crow = buf + llo * CSTR + lhi * 8;
        const ushort_t* w1r  = w1t + llo * CSTR + lhi * 8;
        bf16x8 bc0 = *reinterpret_cast<const bf16x8*>(crow);
        bf16x8 bc1 = *reinterpret_cast<const bf16x8*>(crow + 32);
        bf16x8 bc2 = *reinterpret_cast<const bf16x8*>(crow + 64);
        __builtin_amdgcn_s_setprio(1);
#pragma unroll
        for (int ni = 0; ni < 8; ++ni)
            acc1[ni] = __builtin_amdgcn_mfma_f32_16x16x32_bf16(w1f0[ni], bc0, acc1[ni], 0, 0, 0);
#pragma unroll
        for (int ni = 0; ni < 8; ++ni) {
            bf16x8 afrag = *reinterpret_cast<const bf16x8*>(w1r + ni * 16 * CSTR + 32);
            acc1[ni] = __builtin_amdgcn_mfma_f32_16x16x32_bf16(afrag, bc1, acc1[ni], 0, 0, 0);
        }
#pragma unroll
        for (int ni = 0; ni < 8; ++ni) {
            bf16x8 afrag = *reinterpret_cast<const bf16x8*>(w1r + ni * 16 * CSTR + 64);
            acc1[ni] = __builtin_amdgcn_mfma_f32_16x16x32_bf16(afrag, bc2, acc1[ni], 0, 0, 0);
        }
        __builtin_amdgcn_s_setprio(0);

        // ---- epilogue 1: ReLU + cvt_pk -> h[m][n] (wave-local, no barrier) ----
#pragma unroll
        for (int ni = 0; ni < 8; ++ni) {
            uint2 p;
            p.x = cvt_pk_bf16(fmaxf(acc1[ni][0], 0.f), fmaxf(acc1[ni][1], 0.f));
            p.y = cvt_pk_bf16(fmaxf(acc1[ni][2], 0.f), fmaxf(acc1[ni][3], 0.f));
            *reinterpret_cast<uint2*>(buf + llo * HSTR + ni * 16 + lhi * 4) = p;
        }

        // ---- 5. GEMM2 (A in regs): lane -> out[edge=llo][o=oi*16+lhi*4+j] ----
        f32x4 acc2[2];
        acc2[0] = b2v[0];
        acc2[1] = b2v[1];
        const ushort_t* hrow = buf + llo * HSTR + lhi * 8;
        __builtin_amdgcn_s_setprio(1);
#pragma unroll
        for (int kk = 0; kk < 4; ++kk) {
            bf16x8 bfrag = *reinterpret_cast<const bf16x8*>(hrow + kk * 32);
#pragma unroll
            for (int oi = 0; oi < 2; ++oi)
                acc2[oi] = __builtin_amdgcn_mfma_f32_16x16x32_bf16(w2f[oi][kk], bfrag, acc2[oi], 0, 0, 0);
        }
        __builtin_amdgcn_s_setprio(0);

        // ---- epilogue 2: coalesced dwordx4 store ----
        float* orow = out + (size_t)(t * TILE + w * 16 + llo) * 32 + lhi * 4;
        *reinterpret_cast<f32x4*>(orow)      = acc2[0];
        *reinterpret_cast<f32x4*>(orow + 16) = acc2[1];
    }
}

extern "C" void kernel_launch(void* const* d_in, const int* in_sizes, int n_in,
                              void* d_out, int out_size, void* d_ws, size_t ws_size,
                              hipStream_t stream) {
    const float* edge_feats = (const float*)d_in[0];
    const float* node_feats = (const float*)d_in[1];
    const int*   senders    = (const int*)d_in[2];
    const int*   receivers  = (const int*)d_in[3];
    const float* W1         = (const float*)d_in[4];
    const float* b1         = (const float*)d_in[5];
    const float* W2         = (const float*)d_in[6];
    const float* b2         = (const float*)d_in[7];
    float* out = (float*)d_out;

    dim3 grid(GRID), block(256);
    hipLaunchKernelGGL(edge_mlp_kernel, grid, block, 0, stream,
                       edge_feats, node_feats, senders, receivers, W1, b1, W2, b2, out);
}